// Round 12
// baseline (6652.036 us; speedup 1.0000x reference)
//
#include <hip/hip_runtime.h>
#include <math.h>

#define N_ITERS 200
#define PRECISE_TAIL 4      /* last iterations run split-fp16 compensated */
#define FAST_ITERS (N_ITERS - PRECISE_TAIL)
#define B_DIM 128
#define K_DIM 10000
#define KP2 10240           /* Z cols / Dth cols */
#define KB  10048           /* Dh rows / Wh stride: 314 tiles x 32 */
#define D_DIM 1024
#define ALPHA_F 4.8828125e-6f   /* 0.01 / 2048 */
#define SPLITK 32           /* g1 split-K: 32 slices of 320 (2 blocks/CU) */
#define KSLICE 320
#define NSTEP1 10           /* 320/32 */
#define LSCALE 2048.0f      /* low-part pre-scale (keeps fp16 low normal) */
#define INV_LSCALE 4.8828125e-4f

typedef unsigned short u16;
typedef __attribute__((ext_vector_type(8))) _Float16 f16x8;
typedef __attribute__((ext_vector_type(4))) float f32x4;
#define MFMA16 __builtin_amdgcn_mfma_f32_16x16x32_f16

__device__ __forceinline__ u16 f2h(float x) {
    _Float16 h = (_Float16)x;
    return __builtin_bit_cast(unsigned short, h);
}
__device__ __forceinline__ float h2f(u16 v) {
    _Float16 h = __builtin_bit_cast(_Float16, v);
    return (float)h;
}
// split: x ~= h + l*(1/LSCALE); l stored pre-scaled so it stays fp16-normal
__device__ __forceinline__ void split2h(float x, u16& h, u16& l) {
    u16 hh = f2h(x);
    h = hh;
    l = f2h((x - h2f(hh)) * LSCALE);
}
__device__ __forceinline__ int swz(int r) { return (r & 3) ^ ((r >> 2) & 1); }

__device__ __forceinline__ void gl2lds16(const u16* g, u16* l) {
    __builtin_amdgcn_global_load_lds(
        (const __attribute__((address_space(1))) unsigned int*)g,
        (__attribute__((address_space(3))) unsigned int*)l,
        16, 0, 0);
}

// ---------------------------------------------------------------------------
// GEMM core (fp16): 128(m) x TN(n) tile, 256 threads (4 waves).
// SP=false: plain fp16, 1 MFMA per fragment (FISTA fast path).
// SP=true : split-fp16 compensated; low parts pre-scaled x2048; cross terms
//           accumulate in accC, folded back at the end (x 1/2048).
// NBUF-deep LDS ring, counted vmcnt (never drains to 0 mid-loop);
// lookahead = NBUF-1 stages.
// ---------------------------------------------------------------------------
template<int TN, int KS, bool SP, int NBUF>
__device__ __forceinline__ void gcore(
        const u16* __restrict__ Ahg, const u16* __restrict__ Alg, size_t sA, int arow0,
        const u16* __restrict__ Bhg, const u16* __restrict__ Blg, size_t sB, int brow0,
        size_t k0, int nsteps, u16* lds, int t, f32x4 (*acc)[2]) {
    constexpr int MFRAG = (TN == 64) ? 4 : 2;
    constexpr int P = KS / 32;                    // 32-wide k-panels per step
    constexpr int NA = P * (SP ? 2 : 1);          // A panels (4096 u16 each)
    constexpr int AB0 = NA * 4096;                // B region base (u16)
    constexpr int BPAN = TN * 32;                 // B panel size (u16)
    constexpr int NBP = P * (SP ? 2 : 1);
    constexpr int BUFS = AB0 + NBP * BPAN;        // u16 per ring buffer
    constexpr int LA = 2 * NA;                    // A gl2lds per thread/stage
    constexpr int LB = (TN == 64) ? (SP ? 2 : 1) : 1;
    constexpr int NLD = LA + LB;
    int lane = t & 63, quad = lane >> 4, lr = lane & 15;
    int wv = t >> 6;
    int wm = (TN == 64) ? ((wv >> 1) * 64) : (wv * 32);
    int wn = (TN == 64) ? ((wv & 1) * 32) : 0;
    int r1 = t >> 2, qs = t & 3;
    int q1 = qs ^ swz(r1);
    // A source pointers (pre-swizzled chunk per row)
    const u16* pA[NA][2];
    #pragma unroll
    for (int pa = 0; pa < NA; ++pa) {
        const u16* base = (!SP || pa < P) ? Ahg : Alg;
        size_t kk = k0 + (size_t)(pa % P) * 32;
        pA[pa][0] = base + (size_t)(arow0 + r1) * sA + kk + q1 * 8;
        pA[pa][1] = base + (size_t)(arow0 + r1 + 64) * sA + kk + q1 * 8;
    }
    // B source pointer(s) + LDS dest
    const u16* pB0;
    const u16* pB1 = nullptr;
    int bdst;
    if constexpr (TN == 64) {
        pB0 = Bhg + (size_t)(brow0 + r1) * sB + k0 + q1 * 8;
        if constexpr (SP) pB1 = Blg + (size_t)(brow0 + r1) * sB + k0 + q1 * 8;
        bdst = AB0 + t * 8;
    } else {
        int j = t >> 7;                  // panel idx (KS=64) or h/l (SP)
        int rb = (t & 127) >> 2;
        int qb = qs ^ swz(rb);
        if constexpr (SP) {
            pB0 = (j ? Blg : Bhg) + (size_t)(brow0 + rb) * sB + k0 + qb * 8;
        } else {
            pB0 = Bhg + (size_t)(brow0 + rb) * sB + k0 + (size_t)j * 32 + qb * 8;
        }
        bdst = AB0 + j * BPAN + (t & 127) * 8;
    }
    int dA = t * 8;
    int offA[MFRAG], offB[2];
    #pragma unroll
    for (int mi = 0; mi < MFRAG; ++mi) { int rr = wm + mi * 16 + lr; offA[mi] = rr * 32 + ((quad ^ swz(rr)) * 8); }
    #pragma unroll
    for (int ni = 0; ni < 2; ++ni) { int rr = wn + ni * 16 + lr; offB[ni] = rr * 32 + ((quad ^ swz(rr)) * 8); }
    f32x4 accC[MFRAG][2];
    #pragma unroll
    for (int mi = 0; mi < MFRAG; ++mi)
        #pragma unroll
        for (int ni = 0; ni < 2; ++ni) { acc[mi][ni] = (f32x4){0.f,0.f,0.f,0.f}; accC[mi][ni] = (f32x4){0.f,0.f,0.f,0.f}; }

    auto stage = [&](u16* b, int c) {
        #pragma unroll
        for (int pa = 0; pa < NA; ++pa) {
            gl2lds16(pA[pa][0] + c, b + pa * 4096 + dA);
            gl2lds16(pA[pa][1] + c, b + pa * 4096 + 2048 + dA);
        }
        gl2lds16(pB0 + c, b + bdst);
        if constexpr (TN == 64 && SP) gl2lds16(pB1 + c, b + bdst + BPAN);
    };
    // prologue: NBUF-1 stages in flight
    #pragma unroll
    for (int i = 0; i < NBUF - 1; ++i)
        if (i < nsteps) stage(lds + i * BUFS, i * KS);

    for (int s = 0; s < nsteps; ++s) {
        if (s + NBUF - 1 < nsteps)
            stage(lds + ((s + NBUF - 1) % NBUF) * BUFS, (s + NBUF - 1) * KS);
        int rem = nsteps - 1 - s;   // stages issued ahead of current
        if (rem >= NBUF - 1) {
            asm volatile("s_waitcnt vmcnt(%0)" : : "i"((NBUF - 1) * NLD) : "memory");
        } else if (NBUF >= 5 && rem == 3) {
            asm volatile("s_waitcnt vmcnt(%0)" : : "i"(3 * NLD) : "memory");
        } else if (NBUF >= 4 && rem == 2) {
            asm volatile("s_waitcnt vmcnt(%0)" : : "i"(2 * NLD) : "memory");
        } else if (rem == 1) {
            asm volatile("s_waitcnt vmcnt(%0)" : : "i"(NLD) : "memory");
        } else {
            asm volatile("s_waitcnt vmcnt(0)" : : : "memory");
        }
        __builtin_amdgcn_s_barrier();
        u16* b = lds + (s % NBUF) * BUFS;
        #pragma unroll
        for (int p = 0; p < P; ++p) {
            f16x8 aH[MFRAG], bH[2];
            #pragma unroll
            for (int mi = 0; mi < MFRAG; ++mi) aH[mi] = *(const f16x8*)&b[p * 4096 + offA[mi]];
            #pragma unroll
            for (int ni = 0; ni < 2; ++ni) bH[ni] = *(const f16x8*)&b[AB0 + p * BPAN + offB[ni]];
            if constexpr (SP) {
                f16x8 aL[MFRAG], bL[2];
                #pragma unroll
                for (int mi = 0; mi < MFRAG; ++mi) aL[mi] = *(const f16x8*)&b[(P + p) * 4096 + offA[mi]];
                #pragma unroll
                for (int ni = 0; ni < 2; ++ni) bL[ni] = *(const f16x8*)&b[AB0 + (P + p) * BPAN + offB[ni]];
                #pragma unroll
                for (int mi = 0; mi < MFRAG; ++mi)
                    #pragma unroll
                    for (int ni = 0; ni < 2; ++ni) {
                        acc[mi][ni]  = MFMA16(aH[mi], bH[ni], acc[mi][ni], 0, 0, 0);
                        accC[mi][ni] = MFMA16(aL[mi], bH[ni], accC[mi][ni], 0, 0, 0);
                        accC[mi][ni] = MFMA16(aH[mi], bL[ni], accC[mi][ni], 0, 0, 0);
                    }
            } else {
                #pragma unroll
                for (int mi = 0; mi < MFRAG; ++mi)
                    #pragma unroll
                    for (int ni = 0; ni < 2; ++ni)
                        acc[mi][ni] = MFMA16(aH[mi], bH[ni], acc[mi][ni], 0, 0, 0);
            }
        }
        __builtin_amdgcn_s_barrier();
    }
    if constexpr (SP) {
        #pragma unroll
        for (int mi = 0; mi < MFRAG; ++mi)
            #pragma unroll
            for (int ni = 0; ni < 2; ++ni)
                #pragma unroll
                for (int r = 0; r < 4; ++r)
                    acc[mi][ni][r] += accC[mi][ni][r] * INV_LSCALE;
    }
}

// ---------------------------------------------------------------------------
// init: zero out(+score), Zh/Zl, Wh, u0, scal.  (replay-safe reset)
// ---------------------------------------------------------------------------
__global__ __launch_bounds__(256) void k_init(float* __restrict__ out,
                                              u16* __restrict__ Zh, u16* __restrict__ Zl,
                                              u16* __restrict__ Wh,
                                              float* __restrict__ u0,
                                              float* __restrict__ scal) {
    int idx = blockIdx.x * 256 + threadIdx.x;
    int stride = gridDim.x * 256;
    for (int i = idx; i <= B_DIM * K_DIM; i += stride) out[i] = 0.0f;
    unsigned* zh = (unsigned*)Zh;
    unsigned* zl = (unsigned*)Zl;
    for (int i = idx; i < B_DIM * KP2 / 2; i += stride) { zh[i] = 0u; zl[i] = 0u; }
    unsigned* wh = (unsigned*)Wh;
    for (int i = idx; i < B_DIM * KB / 2; i += stride) wh[i] = 0u;
    for (int i = idx; i < 64; i += stride) scal[i] = 0.0f;
    for (int i = idx; i < D_DIM; i += stride) u0[i] = 0.0f;
}

// ---------------------------------------------------------------------------
// D fp32 -> split-fp16 Dh/Dl [KB,1024] and Dth/Dtl [1024,KP2]
// ---------------------------------------------------------------------------
__global__ __launch_bounds__(256) void k_convertD(const float* __restrict__ D,
                                                  u16* __restrict__ Dh,
                                                  u16* __restrict__ Dl,
                                                  u16* __restrict__ Dth,
                                                  u16* __restrict__ Dtl) {
    __shared__ u16 Th[32][33], Tl[32][33];
    int tx = threadIdx.x & 31, ty = threadIdx.x >> 5;
    int k0 = blockIdx.x * 32, d0 = blockIdx.y * 32;
    #pragma unroll
    for (int r = 0; r < 4; ++r) {
        int krow = k0 + ty + r * 8;
        float val = (krow < K_DIM) ? D[(size_t)krow * D_DIM + d0 + tx] : 0.0f;
        u16 h, l; split2h(val, h, l);
        if (krow < KB) {
            Dh[(size_t)krow * D_DIM + d0 + tx] = h;
            Dl[(size_t)krow * D_DIM + d0 + tx] = l;
        }
        Th[ty + r * 8][tx] = h;
        Tl[ty + r * 8][tx] = l;
    }
    __syncthreads();
    #pragma unroll
    for (int r = 0; r < 4; ++r) {
        int d = d0 + ty + r * 8;
        int k = k0 + tx;
        Dth[(size_t)d * KP2 + k] = Th[tx][ty + r * 8];
        Dtl[(size_t)d * KP2 + k] = Tl[tx][ty + r * 8];
    }
}

// ---------------------------------------------------------------------------
__global__ __launch_bounds__(256) void k_colsum(const float* __restrict__ D,
                                                float* __restrict__ u0) {
    int t = threadIdx.x;
    int kbase = blockIdx.x * 40;
    float a0 = 0.f, a1 = 0.f, a2 = 0.f, a3 = 0.f;
    for (int k = kbase; k < kbase + 40; ++k) {
        const float* row = D + (size_t)k * D_DIM;
        a0 += row[t];
        a1 += row[t + 256];
        a2 += row[t + 512];
        a3 += row[t + 768];
    }
    atomicAdd(&u0[t], a0);
    atomicAdd(&u0[t + 256], a1);
    atomicAdd(&u0[t + 512], a2);
    atomicAdd(&u0[t + 768], a3);
}

// ---------------------------------------------------------------------------
// Gram (2-way split-K): Gp[ks] = Dth @ Dth^T over K=5120 each (compensated).
// grid (16 n, 8 m, 2 ks), partials into scratch (Up).  Full occupancy.
// ---------------------------------------------------------------------------
__global__ __launch_bounds__(256, 2) void k_gram(const u16* __restrict__ Dth,
                                                 const u16* __restrict__ Dtl,
                                                 float* __restrict__ Gp) {
    __shared__ __align__(16) u16 lds[3 * 12288];
    int t = threadIdx.x;
    int n0 = blockIdx.x * 64, m0 = blockIdx.y * 128;
    int ks = blockIdx.z;
    f32x4 acc[4][2];
    gcore<64, 32, true, 3>(Dth, Dtl, KP2, m0, Dth, Dtl, KP2, n0,
                           (size_t)ks * 5120, 160, lds, t, acc);
    int lane = t & 63, quad = lane >> 4, lr = lane & 15;
    int wv = t >> 6;
    int wm = (wv >> 1) * 64, wn = (wv & 1) * 32;
    float* o = Gp + (size_t)ks * (D_DIM * D_DIM);
    #pragma unroll
    for (int mi = 0; mi < 4; ++mi)
        #pragma unroll
        for (int ni = 0; ni < 2; ++ni) {
            int c = n0 + wn + ni * 16 + lr;
            #pragma unroll
            for (int r = 0; r < 4; ++r) {
                int row = m0 + wm + mi * 16 + quad * 4 + r;
                o[(size_t)row * D_DIM + c] = acc[mi][ni][r];
            }
        }
}

// G = Gp0 + Gp1.  grid 1024 x 256, float4.
__global__ __launch_bounds__(256) void k_gsum(const float* __restrict__ Gp,
                                              float* __restrict__ G) {
    int idx = (blockIdx.x * 256 + threadIdx.x) * 4;
    float4 a = *(const float4*)&Gp[idx];
    float4 b = *(const float4*)&Gp[(size_t)(D_DIM * D_DIM) + idx];
    float4 r = {a.x + b.x, a.y + b.y, a.z + b.z, a.w + b.w};
    *(float4*)&G[idx] = r;
}

// ---------------------------------------------------------------------------
__global__ __launch_bounds__(256) void k_pstep(const float* __restrict__ G,
                                               const float* __restrict__ u0,
                                               const float* __restrict__ wvin,
                                               float* __restrict__ wvout,
                                               float* __restrict__ scal, int pw) {
    int t = threadIdx.x;
    int c = blockIdx.x * 4 + (t >> 6);
    int lane = t & 63;
    float rsX = (pw > 0) ? rsqrtf(scal[1 + pw]) : 1.0f;
    float a = 0.f;
    const float* Gr = G + (size_t)c * D_DIM;
    #pragma unroll
    for (int j = 0; j < 16; ++j) {
        int r = lane + j * 64;
        float ur = (pw == 0) ? u0[r] : wvin[r] * rsX;
        a = fmaf(ur, Gr[r], a);
    }
    #pragma unroll
    for (int o = 32; o > 0; o >>= 1) a += __shfl_down(a, o, 64);
    if (lane == 0) {
        float uc = (pw == 0) ? u0[c] : wvin[c] * rsX;
        wvout[c] = a;
        atomicAdd(&scal[2 + pw], a * uc);
    }
}

__global__ void k_Lfin(float* __restrict__ scal) {
    float stepv = 1024.0f / sqrtf(scal[2 + 30]);
    scal[0] = stepv;
    scal[1] = stepv * ALPHA_F;
}

// ---------------------------------------------------------------------------
// Fast G1: Uph[ks] = Z[:, ks*320:+320] @ Dth-slice^T (plain fp16; fp16
// partials).  grid (16, 32) = 512 blocks (2 blocks/CU), XCD-remapped,
// 60 KB LDS (5-deep ring).
// ---------------------------------------------------------------------------
__global__ __launch_bounds__(256, 2) void k_g1f(const u16* __restrict__ Zh,
                                                const u16* __restrict__ Dth,
                                                u16* __restrict__ Uph) {
    __shared__ __align__(16) u16 lds[5 * 6144];
    int t = threadIdx.x;
    int lin = blockIdx.y * 16 + blockIdx.x;
    int rm = (lin & 7) * 64 + (lin >> 3);   // bijective on [0,512)
    int n0 = (rm & 15) * 64;
    int ks = rm >> 4;
    f32x4 acc[4][2];
    gcore<64, 32, false, 5>(Zh, nullptr, KP2, 0, Dth, nullptr, KP2, n0,
                            (size_t)ks * KSLICE, NSTEP1, lds, t, acc);
    int lane = t & 63, quad = lane >> 4, lr = lane & 15;
    int wv = t >> 6;
    int wm = (wv >> 1) * 64, wn = (wv & 1) * 32;
    u16* o = Uph + (size_t)ks * (B_DIM * D_DIM);
    #pragma unroll
    for (int mi = 0; mi < 4; ++mi)
        #pragma unroll
        for (int ni = 0; ni < 2; ++ni) {
            int d = n0 + wn + ni * 16 + lr;
            #pragma unroll
            for (int r = 0; r < 4; ++r) {
                int row = wm + mi * 16 + quad * 4 + r;
                o[(size_t)row * D_DIM + d] = f2h(acc[mi][ni][r]);
            }
        }
}

// ---------------------------------------------------------------------------
// Precise G1 (tail): split-fp16 compensated, fp32 partials.  grid (16, 32).
// ---------------------------------------------------------------------------
__global__ __launch_bounds__(256, 2) void k_g1p(const u16* __restrict__ Zh,
                                                const u16* __restrict__ Zl,
                                                const u16* __restrict__ Dth,
                                                const u16* __restrict__ Dtl,
                                                float* __restrict__ Up) {
    __shared__ __align__(16) u16 lds[3 * 12288];
    int t = threadIdx.x;
    int lin = blockIdx.y * 16 + blockIdx.x;
    int rm = (lin & 7) * 64 + (lin >> 3);
    int n0 = (rm & 15) * 64;
    int ks = rm >> 4;
    f32x4 acc[4][2];
    gcore<64, 32, true, 3>(Zh, Zl, KP2, 0, Dth, Dtl, KP2, n0, (size_t)ks * KSLICE,
                           NSTEP1, lds, t, acc);
    int lane = t & 63, quad = lane >> 4, lr = lane & 15;
    int wv = t >> 6;
    int wm = (wv >> 1) * 64, wn = (wv & 1) * 32;
    float* o = Up + (size_t)ks * (B_DIM * D_DIM);
    #pragma unroll
    for (int mi = 0; mi < 4; ++mi)
        #pragma unroll
        for (int ni = 0; ni < 2; ++ni) {
            int d = n0 + wn + ni * 16 + lr;
            #pragma unroll
            for (int r = 0; r < 4; ++r) {
                int row = wm + mi * 16 + quad * 4 + r;
                o[(size_t)row * D_DIM + d] = acc[mi][ni][r];
            }
        }
}

// ---------------------------------------------------------------------------
// Fast reduce: E = sum(fp16 Uph) - emb -> Eh (fp16).  grid 512 x 256.
// ---------------------------------------------------------------------------
__global__ __launch_bounds__(256) void k_redF(const u16* __restrict__ Uph,
                                              u16* __restrict__ Eh,
                                              const float* __restrict__ emb) {
    int idx = blockIdx.x * 256 + threadIdx.x;   // [0, 131072)
    float v = 0.f;
    #pragma unroll
    for (int s = 0; s < SPLITK; ++s) v += h2f(Uph[(size_t)s * (B_DIM * D_DIM) + idx]);
    Eh[idx] = f2h(v - emb[idx]);
}

// ---------------------------------------------------------------------------
// Precise reduce: E = sum(Up fp32) - emb (or sum if recon) -> split Eh/El.
// grid 512 x 256, 1 elem/thread.
// ---------------------------------------------------------------------------
__global__ __launch_bounds__(256) void k_redP(const float* __restrict__ Up,
                                              u16* __restrict__ Eh,
                                              u16* __restrict__ El,
                                              const float* __restrict__ emb,
                                              int recon) {
    int idx = blockIdx.x * 256 + threadIdx.x;
    float v = 0.f;
    #pragma unroll
    for (int s = 0; s < SPLITK; ++s) v += Up[(size_t)s * (B_DIM * D_DIM) + idx];
    if (!recon) v -= emb[idx];
    u16 h, l; split2h(v, h, l);
    Eh[idx] = h;
    El[idx] = l;
}

// ---------------------------------------------------------------------------
// Fast G2: grad = E@Dh^T/n (plain fp16 KS=64), fused prox, fp16 Zh/Wh state.
// EM=0: steady fast iter.  EM=1: last fast iter -> writes split Z + fp32 W.
// grid (314), 80 KB LDS (4-deep ring), 2 blocks/CU.
// ---------------------------------------------------------------------------
template<int EM>
__global__ __launch_bounds__(256, 2) void k_g2f(const u16* __restrict__ Eh,
                                                const u16* __restrict__ Dh,
                                                u16* __restrict__ Wh,
                                                float* __restrict__ W,
                                                u16* __restrict__ Zh,
                                                u16* __restrict__ Zl,
                                                const float* __restrict__ scal,
                                                float mom) {
    __shared__ __align__(16) u16 lds[4 * 10240];
    int t = threadIdx.x;
    int n0 = blockIdx.x * 32;
    f32x4 acc[2][2];
    gcore<32, 64, false, 4>(Eh, nullptr, D_DIM, 0, Dh, nullptr, D_DIM, n0, 0,
                            16, lds, t, acc);
    int lane = t & 63, quad = lane >> 4, lr = lane & 15;
    int wm = (t >> 6) * 32;
    const float invN = 1.0f / 1024.0f;
    float stepv = scal[0], th = scal[1];
    #pragma unroll
    for (int mi = 0; mi < 2; ++mi)
        #pragma unroll
        for (int ni = 0; ni < 2; ++ni) {
            int k = n0 + ni * 16 + lr;
            #pragma unroll
            for (int r = 0; r < 4; ++r) {
                int i = wm + mi * 16 + quad * 4 + r;
                size_t iz = (size_t)i * KP2 + k;
                float g = acc[mi][ni][r] * invN;
                float z = h2f(Zh[iz]);
                float wold = h2f(Wh[(size_t)i * KB + k]);
                float wnew = fmaxf(z - stepv * g - th, 0.0f);
                float zn = wnew + mom * (wnew - wold);
                if constexpr (EM == 0) {
                    Wh[(size_t)i * KB + k] = f2h(wnew);
                    Zh[iz] = f2h(zn);
                } else {
                    if (k < K_DIM) W[(size_t)i * K_DIM + k] = wnew;
                    u16 h, l; split2h(zn, h, l);
                    Zh[iz] = h; Zl[iz] = l;
                }
            }
        }
}

// ---------------------------------------------------------------------------
// Precise G2 (tail): grad = E@Dh^T/n compensated; prox; split Z + fp32 W.
// grid (314).
// ---------------------------------------------------------------------------
__global__ __launch_bounds__(256, 2) void k_g2p(const u16* __restrict__ Eh,
                                                const u16* __restrict__ El,
                                                const u16* __restrict__ Dh,
                                                const u16* __restrict__ Dl,
                                                float* __restrict__ W,
                                                u16* __restrict__ Zh, u16* __restrict__ Zl,
                                                const float* __restrict__ scal,
                                                float mom, int writeW) {
    __shared__ __align__(16) u16 lds[3 * 10240];
    int t = threadIdx.x;
    int n0 = blockIdx.x * 32;
    f32x4 acc[2][2];
    gcore<32, 32, true, 3>(Eh, El, D_DIM, 0, Dh, Dl, D_DIM, n0, 0, 32, lds, t, acc);
    int lane = t & 63, quad = lane >> 4, lr = lane & 15;
    int wm = (t >> 6) * 32;
    const float invN = 1.0f / 1024.0f;
    float stepv = scal[0], th = scal[1];
    #pragma unroll
    for (int mi = 0; mi < 2; ++mi)
        #pragma unroll
        for (int ni = 0; ni < 2; ++ni) {
            int k = n0 + ni * 16 + lr;
            #pragma unroll
            for (int r = 0; r < 4; ++r) {
                int i = wm + mi * 16 + quad * 4 + r;
                size_t iz = (size_t)i * KP2 + k;
                float g = acc[mi][ni][r] * invN;
                float z = h2f(Zh[iz]) + h2f(Zl[iz]) * INV_LSCALE;
                float wold = (k < K_DIM) ? W[(size_t)i * K_DIM + k] : 0.0f;
                float wnew = fmaxf(z - stepv * g - th, 0.0f);
                float zn = wnew + mom * (wnew - wold);
                if (k < K_DIM) W[(size_t)i * K_DIM + k] = wnew;
                u16 h, l;
                split2h(writeW ? wnew : zn, h, l);
                Zh[iz] = h; Zl[iz] = l;
            }
        }
}

// ---------------------------------------------------------------------------
__global__ __launch_bounds__(256) void k_score(const u16* __restrict__ Eh,
                                               const u16* __restrict__ El,
                                               const float* __restrict__ emb,
                                               float* __restrict__ score) {
    int wid = blockIdx.x * 4 + (threadIdx.x >> 6);
    int lane = threadIdx.x & 63;
    if (wid >= B_DIM) return;
    float rr = 0.f, re = 0.f;
    #pragma unroll
    for (int j = 0; j < D_DIM; j += 64) {
        int idx = wid * D_DIM + j + lane;
        float x = h2f(Eh[idx]) + h2f(El[idx]) * INV_LSCALE;
        rr = fmaf(x, x, rr);
        re = fmaf(x, emb[idx], re);
    }
    #pragma unroll
    for (int off = 32; off > 0; off >>= 1) {
        rr += __shfl_down(rr, off, 64);
        re += __shfl_down(re, off, 64);
    }
    if (lane == 0) atomicAdd(score, re / (sqrtf(rr) + 1e-12f));
}

// ---------------------------------------------------------------------------
extern "C" void kernel_launch(void* const* d_in, const int* in_sizes, int n_in,
                              void* d_out, int out_size, void* d_ws, size_t ws_size,
                              hipStream_t stream) {
    const float* emb = (const float*)d_in[0];   // [128,1024]
    const float* Dm  = (const float*)d_in[1];   // [10000,1024]
    float* out = (float*)d_out;
    float* W = out;                             // [128][10000] in d_out

    size_t off = 0;
    auto carve = [&](size_t bytes) -> void* {
        void* r = (char*)d_ws + off;
        off += (bytes + 255) & ~(size_t)255;
        return r;
    };
    float* G    = (float*)carve((size_t)D_DIM * D_DIM * 4);            // 4.19 MB
    float* Up   = (float*)carve((size_t)SPLITK * B_DIM * D_DIM * 4);   // 16.8 MB
    u16*   Uph  = (u16*)Up;   // alias: fast-path fp16 partials (8.4 MB)
    u16*   Zh   = (u16*)carve((size_t)B_DIM * KP2 * 2);                // 2.62 MB
    u16*   Zl   = (u16*)carve((size_t)B_DIM * KP2 * 2);
    u16*   Wh   = (u16*)carve((size_t)B_DIM * KB * 2);                 // 2.57 MB
    u16*   Eh   = (u16*)carve((size_t)B_DIM * D_DIM * 2);              // 0.26 MB
    u16*   El   = (u16*)carve((size_t)B_DIM * D_DIM * 2);
    float* u0   = (float*)carve(D_DIM * 4);
    float* wva  = (float*)carve(D_DIM * 4);
    float* wvb  = (float*)carve(D_DIM * 4);
    float* scal = (float*)carve(64 * 4);
    u16*   Dh   = (u16*)carve((size_t)KB * D_DIM * 2);                 // 20.6 MB
    u16*   Dl   = (u16*)carve((size_t)KB * D_DIM * 2);
    u16*   Dth  = (u16*)carve((size_t)D_DIM * KP2 * 2);                // 21.0 MB
    u16*   Dtl  = (u16*)carve((size_t)D_DIM * KP2 * 2);

    k_init<<<512, 256, 0, stream>>>(out, Zh, Zl, Wh, u0, scal);
    k_convertD<<<dim3(320, 32), 256, 0, stream>>>(Dm, Dh, Dl, Dth, Dtl);
    k_colsum<<<250, 256, 0, stream>>>(Dm, u0);
    // Gram with 2-way split-K into Up scratch (used before FISTA), then sum.
    k_gram<<<dim3(16, 8, 2), 256, 0, stream>>>(Dth, Dtl, Up);
    k_gsum<<<1024, 256, 0, stream>>>(Up, G);

    // ---- power iteration in u-space on the 1024x1024 Gram ----
    for (int pw = 0; pw <= 30; ++pw) {
        float* win  = (pw & 1) ? wva : wvb;
        float* wout = (pw & 1) ? wvb : wva;
        k_pstep<<<256, 256, 0, stream>>>(G, u0, win, wout, scal, pw);
    }
    k_Lfin<<<1, 1, 0, stream>>>(scal);

    // ---- FISTA: fast fp16 iters (3 launches/iter), compensated tail ----
    double t = 1.0;
    for (int it = 0; it < N_ITERS; ++it) {
        double tn = 0.5 * (1.0 + sqrt(1.0 + 4.0 * t * t));
        float mom = (float)((t - 1.0) / tn);
        t = tn;
        if (it < FAST_ITERS) {
            k_g1f<<<dim3(16, SPLITK), 256, 0, stream>>>(Zh, Dth, Uph);
            k_redF<<<512, 256, 0, stream>>>(Uph, Eh, emb);
            if (it == FAST_ITERS - 1)
                k_g2f<1><<<dim3(314, 1), 256, 0, stream>>>(Eh, Dh, Wh, W,
                                                           Zh, Zl, scal, mom);
            else
                k_g2f<0><<<dim3(314, 1), 256, 0, stream>>>(Eh, Dh, Wh, W,
                                                           Zh, Zl, scal, mom);
        } else {
            k_g1p<<<dim3(16, SPLITK), 256, 0, stream>>>(Zh, Zl, Dth, Dtl, Up);
            k_redP<<<512, 256, 0, stream>>>(Up, Eh, El, emb, 0);
            k_g2p<<<dim3(314, 1), 256, 0, stream>>>(Eh, El, Dh, Dl, W, Zh, Zl,
                                                    scal, mom,
                                                    (it == N_ITERS - 1) ? 1 : 0);
        }
    }

    // ---- recon = W@D (Zh/Zl hold split W), score ----
    k_g1p<<<dim3(16, SPLITK), 256, 0, stream>>>(Zh, Zl, Dth, Dtl, Up);
    k_redP<<<512, 256, 0, stream>>>(Up, Eh, El, emb, 1);
    k_score<<<32, 256, 0, stream>>>(Eh, El, emb, out + (size_t)B_DIM * K_DIM);
}

// Round 13
// 6531.527 us; speedup vs baseline: 1.0185x; 1.0185x over previous
//
#include <hip/hip_runtime.h>
#include <math.h>

#define N_ITERS 200
#define PRECISE_TAIL 3      /* last iterations run split-fp16 compensated */
#define FAST_ITERS (N_ITERS - PRECISE_TAIL)
#define B_DIM 128
#define K_DIM 10000
#define KP2 10240           /* Z cols / Dth cols */
#define KB  10048           /* Dh rows / Wh stride: 314 tiles x 32 */
#define D_DIM 1024
#define ALPHA_F 4.8828125e-6f   /* 0.01 / 2048 */
#define SPLITK 16           /* g1 split-K: 16 slices of 640 */
#define KSLICE 640
#define NSTEP1 20           /* 640/32 */
#define LSCALE 2048.0f      /* low-part pre-scale (keeps fp16 low normal) */
#define INV_LSCALE 4.8828125e-4f

typedef unsigned short u16;
typedef __attribute__((ext_vector_type(8))) _Float16 f16x8;
typedef __attribute__((ext_vector_type(4))) float f32x4;
#define MFMA16 __builtin_amdgcn_mfma_f32_16x16x32_f16

__device__ __forceinline__ u16 f2h(float x) {
    _Float16 h = (_Float16)x;
    return __builtin_bit_cast(unsigned short, h);
}
__device__ __forceinline__ float h2f(u16 v) {
    _Float16 h = __builtin_bit_cast(_Float16, v);
    return (float)h;
}
// split: x ~= h + l*(1/LSCALE); l stored pre-scaled so it stays fp16-normal
__device__ __forceinline__ void split2h(float x, u16& h, u16& l) {
    u16 hh = f2h(x);
    h = hh;
    l = f2h((x - h2f(hh)) * LSCALE);
}
__device__ __forceinline__ int swz(int r) { return (r & 3) ^ ((r >> 2) & 1); }

__device__ __forceinline__ void gl2lds16(const u16* g, u16* l) {
    __builtin_amdgcn_global_load_lds(
        (const __attribute__((address_space(1))) unsigned int*)g,
        (__attribute__((address_space(3))) unsigned int*)l,
        16, 0, 0);
}

// ---------------------------------------------------------------------------
// GEMM core (fp16): 128(m) x TN(n) tile, 256 threads (4 waves).
// SP=false: plain fp16, 1 MFMA per fragment (FISTA fast path).
// SP=true : split-fp16 compensated; low parts pre-scaled x2048; cross terms
//           accumulate in accC, folded back at the end (x 1/2048).
// NBUF-deep LDS ring, counted vmcnt (never drains to 0 mid-loop);
// lookahead = NBUF-1 stages.
// ---------------------------------------------------------------------------
template<int TN, int KS, bool SP, int NBUF>
__device__ __forceinline__ void gcore(
        const u16* __restrict__ Ahg, const u16* __restrict__ Alg, size_t sA, int arow0,
        const u16* __restrict__ Bhg, const u16* __restrict__ Blg, size_t sB, int brow0,
        size_t k0, int nsteps, u16* lds, int t, f32x4 (*acc)[2]) {
    constexpr int MFRAG = (TN == 64) ? 4 : 2;
    constexpr int P = KS / 32;                    // 32-wide k-panels per step
    constexpr int NA = P * (SP ? 2 : 1);          // A panels (4096 u16 each)
    constexpr int AB0 = NA * 4096;                // B region base (u16)
    constexpr int BPAN = TN * 32;                 // B panel size (u16)
    constexpr int NBP = P * (SP ? 2 : 1);
    constexpr int BUFS = AB0 + NBP * BPAN;        // u16 per ring buffer
    constexpr int LA = 2 * NA;                    // A gl2lds per thread/stage
    constexpr int LB = (TN == 64) ? (SP ? 2 : 1) : 1;
    constexpr int NLD = LA + LB;
    int lane = t & 63, quad = lane >> 4, lr = lane & 15;
    int wv = t >> 6;
    int wm = (TN == 64) ? ((wv >> 1) * 64) : (wv * 32);
    int wn = (TN == 64) ? ((wv & 1) * 32) : 0;
    int r1 = t >> 2, qs = t & 3;
    int q1 = qs ^ swz(r1);
    // A source pointers (pre-swizzled chunk per row)
    const u16* pA[NA][2];
    #pragma unroll
    for (int pa = 0; pa < NA; ++pa) {
        const u16* base = (!SP || pa < P) ? Ahg : Alg;
        size_t kk = k0 + (size_t)(pa % P) * 32;
        pA[pa][0] = base + (size_t)(arow0 + r1) * sA + kk + q1 * 8;
        pA[pa][1] = base + (size_t)(arow0 + r1 + 64) * sA + kk + q1 * 8;
    }
    // B source pointer(s) + LDS dest
    const u16* pB0;
    const u16* pB1 = nullptr;
    int bdst;
    if constexpr (TN == 64) {
        pB0 = Bhg + (size_t)(brow0 + r1) * sB + k0 + q1 * 8;
        if constexpr (SP) pB1 = Blg + (size_t)(brow0 + r1) * sB + k0 + q1 * 8;
        bdst = AB0 + t * 8;
    } else {
        int j = t >> 7;                  // panel idx (KS=64) or h/l (SP)
        int rb = (t & 127) >> 2;
        int qb = qs ^ swz(rb);
        if constexpr (SP) {
            pB0 = (j ? Blg : Bhg) + (size_t)(brow0 + rb) * sB + k0 + qb * 8;
        } else {
            pB0 = Bhg + (size_t)(brow0 + rb) * sB + k0 + (size_t)j * 32 + qb * 8;
        }
        bdst = AB0 + j * BPAN + (t & 127) * 8;
    }
    int dA = t * 8;
    int offA[MFRAG], offB[2];
    #pragma unroll
    for (int mi = 0; mi < MFRAG; ++mi) { int rr = wm + mi * 16 + lr; offA[mi] = rr * 32 + ((quad ^ swz(rr)) * 8); }
    #pragma unroll
    for (int ni = 0; ni < 2; ++ni) { int rr = wn + ni * 16 + lr; offB[ni] = rr * 32 + ((quad ^ swz(rr)) * 8); }
    f32x4 accC[MFRAG][2];
    #pragma unroll
    for (int mi = 0; mi < MFRAG; ++mi)
        #pragma unroll
        for (int ni = 0; ni < 2; ++ni) { acc[mi][ni] = (f32x4){0.f,0.f,0.f,0.f}; accC[mi][ni] = (f32x4){0.f,0.f,0.f,0.f}; }

    auto stage = [&](u16* b, int c) {
        #pragma unroll
        for (int pa = 0; pa < NA; ++pa) {
            gl2lds16(pA[pa][0] + c, b + pa * 4096 + dA);
            gl2lds16(pA[pa][1] + c, b + pa * 4096 + 2048 + dA);
        }
        gl2lds16(pB0 + c, b + bdst);
        if constexpr (TN == 64 && SP) gl2lds16(pB1 + c, b + bdst + BPAN);
    };
    // prologue: NBUF-1 stages in flight
    #pragma unroll
    for (int i = 0; i < NBUF - 1; ++i)
        if (i < nsteps) stage(lds + i * BUFS, i * KS);

    for (int s = 0; s < nsteps; ++s) {
        if (s + NBUF - 1 < nsteps)
            stage(lds + ((s + NBUF - 1) % NBUF) * BUFS, (s + NBUF - 1) * KS);
        int rem = nsteps - 1 - s;   // stages issued ahead of current
        if (rem >= NBUF - 1) {
            asm volatile("s_waitcnt vmcnt(%0)" : : "i"((NBUF - 1) * NLD) : "memory");
        } else if (NBUF >= 5 && rem == 3) {
            asm volatile("s_waitcnt vmcnt(%0)" : : "i"(3 * NLD) : "memory");
        } else if (NBUF >= 4 && rem == 2) {
            asm volatile("s_waitcnt vmcnt(%0)" : : "i"(2 * NLD) : "memory");
        } else if (rem == 1) {
            asm volatile("s_waitcnt vmcnt(%0)" : : "i"(NLD) : "memory");
        } else {
            asm volatile("s_waitcnt vmcnt(0)" : : : "memory");
        }
        __builtin_amdgcn_s_barrier();
        u16* b = lds + (s % NBUF) * BUFS;
        #pragma unroll
        for (int p = 0; p < P; ++p) {
            f16x8 aH[MFRAG], bH[2];
            #pragma unroll
            for (int mi = 0; mi < MFRAG; ++mi) aH[mi] = *(const f16x8*)&b[p * 4096 + offA[mi]];
            #pragma unroll
            for (int ni = 0; ni < 2; ++ni) bH[ni] = *(const f16x8*)&b[AB0 + p * BPAN + offB[ni]];
            if constexpr (SP) {
                f16x8 aL[MFRAG], bL[2];
                #pragma unroll
                for (int mi = 0; mi < MFRAG; ++mi) aL[mi] = *(const f16x8*)&b[(P + p) * 4096 + offA[mi]];
                #pragma unroll
                for (int ni = 0; ni < 2; ++ni) bL[ni] = *(const f16x8*)&b[AB0 + (P + p) * BPAN + offB[ni]];
                #pragma unroll
                for (int mi = 0; mi < MFRAG; ++mi)
                    #pragma unroll
                    for (int ni = 0; ni < 2; ++ni) {
                        acc[mi][ni]  = MFMA16(aH[mi], bH[ni], acc[mi][ni], 0, 0, 0);
                        accC[mi][ni] = MFMA16(aL[mi], bH[ni], accC[mi][ni], 0, 0, 0);
                        accC[mi][ni] = MFMA16(aH[mi], bL[ni], accC[mi][ni], 0, 0, 0);
                    }
            } else {
                #pragma unroll
                for (int mi = 0; mi < MFRAG; ++mi)
                    #pragma unroll
                    for (int ni = 0; ni < 2; ++ni)
                        acc[mi][ni] = MFMA16(aH[mi], bH[ni], acc[mi][ni], 0, 0, 0);
            }
        }
        __builtin_amdgcn_s_barrier();
    }
    if constexpr (SP) {
        #pragma unroll
        for (int mi = 0; mi < MFRAG; ++mi)
            #pragma unroll
            for (int ni = 0; ni < 2; ++ni)
                #pragma unroll
                for (int r = 0; r < 4; ++r)
                    acc[mi][ni][r] += accC[mi][ni][r] * INV_LSCALE;
    }
}

// ---------------------------------------------------------------------------
// init: zero out(+score), Zh/Zl, Wh, u0, scal.  (replay-safe reset)
// ---------------------------------------------------------------------------
__global__ __launch_bounds__(256) void k_init(float* __restrict__ out,
                                              u16* __restrict__ Zh, u16* __restrict__ Zl,
                                              u16* __restrict__ Wh,
                                              float* __restrict__ u0,
                                              float* __restrict__ scal) {
    int idx = blockIdx.x * 256 + threadIdx.x;
    int stride = gridDim.x * 256;
    for (int i = idx; i <= B_DIM * K_DIM; i += stride) out[i] = 0.0f;
    unsigned* zh = (unsigned*)Zh;
    unsigned* zl = (unsigned*)Zl;
    for (int i = idx; i < B_DIM * KP2 / 2; i += stride) { zh[i] = 0u; zl[i] = 0u; }
    unsigned* wh = (unsigned*)Wh;
    for (int i = idx; i < B_DIM * KB / 2; i += stride) wh[i] = 0u;
    for (int i = idx; i < 64; i += stride) scal[i] = 0.0f;
    for (int i = idx; i < D_DIM; i += stride) u0[i] = 0.0f;
}

// ---------------------------------------------------------------------------
// D fp32 -> split-fp16 Dh/Dl [KB,1024] and Dth/Dtl [1024,KP2]
// ---------------------------------------------------------------------------
__global__ __launch_bounds__(256) void k_convertD(const float* __restrict__ D,
                                                  u16* __restrict__ Dh,
                                                  u16* __restrict__ Dl,
                                                  u16* __restrict__ Dth,
                                                  u16* __restrict__ Dtl) {
    __shared__ u16 Th[32][33], Tl[32][33];
    int tx = threadIdx.x & 31, ty = threadIdx.x >> 5;
    int k0 = blockIdx.x * 32, d0 = blockIdx.y * 32;
    #pragma unroll
    for (int r = 0; r < 4; ++r) {
        int krow = k0 + ty + r * 8;
        float val = (krow < K_DIM) ? D[(size_t)krow * D_DIM + d0 + tx] : 0.0f;
        u16 h, l; split2h(val, h, l);
        if (krow < KB) {
            Dh[(size_t)krow * D_DIM + d0 + tx] = h;
            Dl[(size_t)krow * D_DIM + d0 + tx] = l;
        }
        Th[ty + r * 8][tx] = h;
        Tl[ty + r * 8][tx] = l;
    }
    __syncthreads();
    #pragma unroll
    for (int r = 0; r < 4; ++r) {
        int d = d0 + ty + r * 8;
        int k = k0 + tx;
        Dth[(size_t)d * KP2 + k] = Th[tx][ty + r * 8];
        Dtl[(size_t)d * KP2 + k] = Tl[tx][ty + r * 8];
    }
}

// ---------------------------------------------------------------------------
__global__ __launch_bounds__(256) void k_colsum(const float* __restrict__ D,
                                                float* __restrict__ u0) {
    int t = threadIdx.x;
    int kbase = blockIdx.x * 40;
    float a0 = 0.f, a1 = 0.f, a2 = 0.f, a3 = 0.f;
    for (int k = kbase; k < kbase + 40; ++k) {
        const float* row = D + (size_t)k * D_DIM;
        a0 += row[t];
        a1 += row[t + 256];
        a2 += row[t + 512];
        a3 += row[t + 768];
    }
    atomicAdd(&u0[t], a0);
    atomicAdd(&u0[t + 256], a1);
    atomicAdd(&u0[t + 512], a2);
    atomicAdd(&u0[t + 768], a3);
}

// ---------------------------------------------------------------------------
// Gram (2-way split-K): Gp[ks] = Dth @ Dth^T over K=5120 each (compensated).
// grid (16 n, 8 m, 2 ks), partials into scratch (Up).  Full occupancy.
// ---------------------------------------------------------------------------
__global__ __launch_bounds__(256, 2) void k_gram(const u16* __restrict__ Dth,
                                                 const u16* __restrict__ Dtl,
                                                 float* __restrict__ Gp) {
    __shared__ __align__(16) u16 lds[3 * 12288];
    int t = threadIdx.x;
    int n0 = blockIdx.x * 64, m0 = blockIdx.y * 128;
    int ks = blockIdx.z;
    f32x4 acc[4][2];
    gcore<64, 32, true, 3>(Dth, Dtl, KP2, m0, Dth, Dtl, KP2, n0,
                           (size_t)ks * 5120, 160, lds, t, acc);
    int lane = t & 63, quad = lane >> 4, lr = lane & 15;
    int wv = t >> 6;
    int wm = (wv >> 1) * 64, wn = (wv & 1) * 32;
    float* o = Gp + (size_t)ks * (D_DIM * D_DIM);
    #pragma unroll
    for (int mi = 0; mi < 4; ++mi)
        #pragma unroll
        for (int ni = 0; ni < 2; ++ni) {
            int c = n0 + wn + ni * 16 + lr;
            #pragma unroll
            for (int r = 0; r < 4; ++r) {
                int row = m0 + wm + mi * 16 + quad * 4 + r;
                o[(size_t)row * D_DIM + c] = acc[mi][ni][r];
            }
        }
}

// G = Gp0 + Gp1.  grid 1024 x 256, float4.
__global__ __launch_bounds__(256) void k_gsum(const float* __restrict__ Gp,
                                              float* __restrict__ G) {
    int idx = (blockIdx.x * 256 + threadIdx.x) * 4;
    float4 a = *(const float4*)&Gp[idx];
    float4 b = *(const float4*)&Gp[(size_t)(D_DIM * D_DIM) + idx];
    float4 r = {a.x + b.x, a.y + b.y, a.z + b.z, a.w + b.w};
    *(float4*)&G[idx] = r;
}

// ---------------------------------------------------------------------------
__global__ __launch_bounds__(256) void k_pstep(const float* __restrict__ G,
                                               const float* __restrict__ u0,
                                               const float* __restrict__ wvin,
                                               float* __restrict__ wvout,
                                               float* __restrict__ scal, int pw) {
    int t = threadIdx.x;
    int c = blockIdx.x * 4 + (t >> 6);
    int lane = t & 63;
    float rsX = (pw > 0) ? rsqrtf(scal[1 + pw]) : 1.0f;
    float a = 0.f;
    const float* Gr = G + (size_t)c * D_DIM;
    #pragma unroll
    for (int j = 0; j < 16; ++j) {
        int r = lane + j * 64;
        float ur = (pw == 0) ? u0[r] : wvin[r] * rsX;
        a = fmaf(ur, Gr[r], a);
    }
    #pragma unroll
    for (int o = 32; o > 0; o >>= 1) a += __shfl_down(a, o, 64);
    if (lane == 0) {
        float uc = (pw == 0) ? u0[c] : wvin[c] * rsX;
        wvout[c] = a;
        atomicAdd(&scal[2 + pw], a * uc);
    }
}

__global__ void k_Lfin(float* __restrict__ scal) {
    float stepv = 1024.0f / sqrtf(scal[2 + 30]);
    scal[0] = stepv;
    scal[1] = stepv * ALPHA_F;
}

// ---------------------------------------------------------------------------
// Fast G1: Uph[ks] = Z[:, ks*640:+640] @ Dth-slice^T (plain fp16; fp16
// partials).  grid (16, 16) XCD-remapped, 60 KB LDS (5-deep ring).
// ---------------------------------------------------------------------------
__global__ __launch_bounds__(256, 2) void k_g1f(const u16* __restrict__ Zh,
                                                const u16* __restrict__ Dth,
                                                u16* __restrict__ Uph) {
    __shared__ __align__(16) u16 lds[5 * 6144];
    int t = threadIdx.x;
    int lin = blockIdx.y * 16 + blockIdx.x;
    int rm = (lin & 7) * 32 + (lin >> 3);   // bijective on [0,256)
    int n0 = (rm & 15) * 64;
    int ks = rm >> 4;
    f32x4 acc[4][2];
    gcore<64, 32, false, 5>(Zh, nullptr, KP2, 0, Dth, nullptr, KP2, n0,
                            (size_t)ks * KSLICE, NSTEP1, lds, t, acc);
    int lane = t & 63, quad = lane >> 4, lr = lane & 15;
    int wv = t >> 6;
    int wm = (wv >> 1) * 64, wn = (wv & 1) * 32;
    u16* o = Uph + (size_t)ks * (B_DIM * D_DIM);
    #pragma unroll
    for (int mi = 0; mi < 4; ++mi)
        #pragma unroll
        for (int ni = 0; ni < 2; ++ni) {
            int d = n0 + wn + ni * 16 + lr;
            #pragma unroll
            for (int r = 0; r < 4; ++r) {
                int row = wm + mi * 16 + quad * 4 + r;
                o[(size_t)row * D_DIM + d] = f2h(acc[mi][ni][r]);
            }
        }
}

// ---------------------------------------------------------------------------
// Precise G1 (tail): split-fp16 compensated, fp32 partials.  grid (16, 16).
// ---------------------------------------------------------------------------
__global__ __launch_bounds__(256, 2) void k_g1p(const u16* __restrict__ Zh,
                                                const u16* __restrict__ Zl,
                                                const u16* __restrict__ Dth,
                                                const u16* __restrict__ Dtl,
                                                float* __restrict__ Up) {
    __shared__ __align__(16) u16 lds[3 * 12288];
    int t = threadIdx.x;
    int lin = blockIdx.y * 16 + blockIdx.x;
    int rm = (lin & 7) * 32 + (lin >> 3);
    int n0 = (rm & 15) * 64;
    int ks = rm >> 4;
    f32x4 acc[4][2];
    gcore<64, 32, true, 3>(Zh, Zl, KP2, 0, Dth, Dtl, KP2, n0, (size_t)ks * KSLICE,
                           NSTEP1, lds, t, acc);
    int lane = t & 63, quad = lane >> 4, lr = lane & 15;
    int wv = t >> 6;
    int wm = (wv >> 1) * 64, wn = (wv & 1) * 32;
    float* o = Up + (size_t)ks * (B_DIM * D_DIM);
    #pragma unroll
    for (int mi = 0; mi < 4; ++mi)
        #pragma unroll
        for (int ni = 0; ni < 2; ++ni) {
            int d = n0 + wn + ni * 16 + lr;
            #pragma unroll
            for (int r = 0; r < 4; ++r) {
                int row = wm + mi * 16 + quad * 4 + r;
                o[(size_t)row * D_DIM + d] = acc[mi][ni][r];
            }
        }
}

// ---------------------------------------------------------------------------
// Fast reduce: E = sum(fp16 Uph) - emb -> Eh (fp16).  grid 512 x 256.
// ---------------------------------------------------------------------------
__global__ __launch_bounds__(256) void k_redF(const u16* __restrict__ Uph,
                                              u16* __restrict__ Eh,
                                              const float* __restrict__ emb) {
    int idx = blockIdx.x * 256 + threadIdx.x;   // [0, 131072)
    float v = 0.f;
    #pragma unroll
    for (int s = 0; s < SPLITK; ++s) v += h2f(Uph[(size_t)s * (B_DIM * D_DIM) + idx]);
    Eh[idx] = f2h(v - emb[idx]);
}

// ---------------------------------------------------------------------------
// Precise reduce: E = sum(Up fp32) - emb (or sum if recon) -> split Eh/El.
// grid 512 x 256, 1 elem/thread.
// ---------------------------------------------------------------------------
__global__ __launch_bounds__(256) void k_redP(const float* __restrict__ Up,
                                              u16* __restrict__ Eh,
                                              u16* __restrict__ El,
                                              const float* __restrict__ emb,
                                              int recon) {
    int idx = blockIdx.x * 256 + threadIdx.x;
    float v = 0.f;
    #pragma unroll
    for (int s = 0; s < SPLITK; ++s) v += Up[(size_t)s * (B_DIM * D_DIM) + idx];
    if (!recon) v -= emb[idx];
    u16 h, l; split2h(v, h, l);
    Eh[idx] = h;
    El[idx] = l;
}

// ---------------------------------------------------------------------------
// Fast G2: grad = E@Dh^T/n (plain fp16 KS=64), fused prox, fp16 Zh/Wh state.
// EM=0: steady fast iter.  EM=1: last fast iter -> writes split Z + fp32 W.
// grid (314), 80 KB LDS (4-deep ring), 2 blocks/CU.
// ---------------------------------------------------------------------------
template<int EM>
__global__ __launch_bounds__(256, 2) void k_g2f(const u16* __restrict__ Eh,
                                                const u16* __restrict__ Dh,
                                                u16* __restrict__ Wh,
                                                float* __restrict__ W,
                                                u16* __restrict__ Zh,
                                                u16* __restrict__ Zl,
                                                const float* __restrict__ scal,
                                                float mom) {
    __shared__ __align__(16) u16 lds[4 * 10240];
    int t = threadIdx.x;
    int n0 = blockIdx.x * 32;
    f32x4 acc[2][2];
    gcore<32, 64, false, 4>(Eh, nullptr, D_DIM, 0, Dh, nullptr, D_DIM, n0, 0,
                            16, lds, t, acc);
    int lane = t & 63, quad = lane >> 4, lr = lane & 15;
    int wm = (t >> 6) * 32;
    const float invN = 1.0f / 1024.0f;
    float stepv = scal[0], th = scal[1];
    #pragma unroll
    for (int mi = 0; mi < 2; ++mi)
        #pragma unroll
        for (int ni = 0; ni < 2; ++ni) {
            int k = n0 + ni * 16 + lr;
            #pragma unroll
            for (int r = 0; r < 4; ++r) {
                int i = wm + mi * 16 + quad * 4 + r;
                size_t iz = (size_t)i * KP2 + k;
                float g = acc[mi][ni][r] * invN;
                float z = h2f(Zh[iz]);
                float wold = h2f(Wh[(size_t)i * KB + k]);
                float wnew = fmaxf(z - stepv * g - th, 0.0f);
                float zn = wnew + mom * (wnew - wold);
                if constexpr (EM == 0) {
                    Wh[(size_t)i * KB + k] = f2h(wnew);
                    Zh[iz] = f2h(zn);
                } else {
                    if (k < K_DIM) W[(size_t)i * K_DIM + k] = wnew;
                    u16 h, l; split2h(zn, h, l);
                    Zh[iz] = h; Zl[iz] = l;
                }
            }
        }
}

// ---------------------------------------------------------------------------
// Precise G2 (tail): grad = E@Dh^T/n compensated; prox; split Z + fp32 W.
// grid (314).
// ---------------------------------------------------------------------------
__global__ __launch_bounds__(256, 2) void k_g2p(const u16* __restrict__ Eh,
                                                const u16* __restrict__ El,
                                                const u16* __restrict__ Dh,
                                                const u16* __restrict__ Dl,
                                                float* __restrict__ W,
                                                u16* __restrict__ Zh, u16* __restrict__ Zl,
                                                const float* __restrict__ scal,
                                                float mom, int writeW) {
    __shared__ __align__(16) u16 lds[3 * 10240];
    int t = threadIdx.x;
    int n0 = blockIdx.x * 32;
    f32x4 acc[2][2];
    gcore<32, 32, true, 3>(Eh, El, D_DIM, 0, Dh, Dl, D_DIM, n0, 0, 32, lds, t, acc);
    int lane = t & 63, quad = lane >> 4, lr = lane & 15;
    int wm = (t >> 6) * 32;
    const float invN = 1.0f / 1024.0f;
    float stepv = scal[0], th = scal[1];
    #pragma unroll
    for (int mi = 0; mi < 2; ++mi)
        #pragma unroll
        for (int ni = 0; ni < 2; ++ni) {
            int k = n0 + ni * 16 + lr;
            #pragma unroll
            for (int r = 0; r < 4; ++r) {
                int i = wm + mi * 16 + quad * 4 + r;
                size_t iz = (size_t)i * KP2 + k;
                float g = acc[mi][ni][r] * invN;
                float z = h2f(Zh[iz]) + h2f(Zl[iz]) * INV_LSCALE;
                float wold = (k < K_DIM) ? W[(size_t)i * K_DIM + k] : 0.0f;
                float wnew = fmaxf(z - stepv * g - th, 0.0f);
                float zn = wnew + mom * (wnew - wold);
                if (k < K_DIM) W[(size_t)i * K_DIM + k] = wnew;
                u16 h, l;
                split2h(writeW ? wnew : zn, h, l);
                Zh[iz] = h; Zl[iz] = l;
            }
        }
}

// ---------------------------------------------------------------------------
__global__ __launch_bounds__(256) void k_score(const u16* __restrict__ Eh,
                                               const u16* __restrict__ El,
                                               const float* __restrict__ emb,
                                               float* __restrict__ score) {
    int wid = blockIdx.x * 4 + (threadIdx.x >> 6);
    int lane = threadIdx.x & 63;
    if (wid >= B_DIM) return;
    float rr = 0.f, re = 0.f;
    #pragma unroll
    for (int j = 0; j < D_DIM; j += 64) {
        int idx = wid * D_DIM + j + lane;
        float x = h2f(Eh[idx]) + h2f(El[idx]) * INV_LSCALE;
        rr = fmaf(x, x, rr);
        re = fmaf(x, emb[idx], re);
    }
    #pragma unroll
    for (int off = 32; off > 0; off >>= 1) {
        rr += __shfl_down(rr, off, 64);
        re += __shfl_down(re, off, 64);
    }
    if (lane == 0) atomicAdd(score, re / (sqrtf(rr) + 1e-12f));
}

// ---------------------------------------------------------------------------
extern "C" void kernel_launch(void* const* d_in, const int* in_sizes, int n_in,
                              void* d_out, int out_size, void* d_ws, size_t ws_size,
                              hipStream_t stream) {
    const float* emb = (const float*)d_in[0];   // [128,1024]
    const float* Dm  = (const float*)d_in[1];   // [10000,1024]
    float* out = (float*)d_out;
    float* W = out;                             // [128][10000] in d_out

    size_t off = 0;
    auto carve = [&](size_t bytes) -> void* {
        void* r = (char*)d_ws + off;
        off += (bytes + 255) & ~(size_t)255;
        return r;
    };
    float* G    = (float*)carve((size_t)D_DIM * D_DIM * 4);            // 4.19 MB
    float* Up   = (float*)carve((size_t)SPLITK * B_DIM * D_DIM * 4);   // 8.39 MB
    u16*   Uph  = (u16*)Up;   // alias: fast-path fp16 partials (4.2 MB)
    u16*   Zh   = (u16*)carve((size_t)B_DIM * KP2 * 2);                // 2.62 MB
    u16*   Zl   = (u16*)carve((size_t)B_DIM * KP2 * 2);
    u16*   Wh   = (u16*)carve((size_t)B_DIM * KB * 2);                 // 2.57 MB
    u16*   Eh   = (u16*)carve((size_t)B_DIM * D_DIM * 2);              // 0.26 MB
    u16*   El   = (u16*)carve((size_t)B_DIM * D_DIM * 2);
    float* u0   = (float*)carve(D_DIM * 4);
    float* wva  = (float*)carve(D_DIM * 4);
    float* wvb  = (float*)carve(D_DIM * 4);
    float* scal = (float*)carve(64 * 4);
    u16*   Dh   = (u16*)carve((size_t)KB * D_DIM * 2);                 // 20.6 MB
    u16*   Dl   = (u16*)carve((size_t)KB * D_DIM * 2);
    u16*   Dth  = (u16*)carve((size_t)D_DIM * KP2 * 2);                // 21.0 MB
    u16*   Dtl  = (u16*)carve((size_t)D_DIM * KP2 * 2);

    k_init<<<512, 256, 0, stream>>>(out, Zh, Zl, Wh, u0, scal);
    k_convertD<<<dim3(320, 32), 256, 0, stream>>>(Dm, Dh, Dl, Dth, Dtl);
    k_colsum<<<250, 256, 0, stream>>>(Dm, u0);
    // Gram with 2-way split-K into Up scratch (used before FISTA), then sum.
    k_gram<<<dim3(16, 8, 2), 256, 0, stream>>>(Dth, Dtl, Up);
    k_gsum<<<1024, 256, 0, stream>>>(Up, G);

    // ---- power iteration in u-space on the 1024x1024 Gram ----
    for (int pw = 0; pw <= 30; ++pw) {
        float* win  = (pw & 1) ? wva : wvb;
        float* wout = (pw & 1) ? wvb : wva;
        k_pstep<<<256, 256, 0, stream>>>(G, u0, win, wout, scal, pw);
    }
    k_Lfin<<<1, 1, 0, stream>>>(scal);

    // ---- FISTA: fast fp16 iters (3 launches/iter), compensated tail ----
    double t = 1.0;
    for (int it = 0; it < N_ITERS; ++it) {
        double tn = 0.5 * (1.0 + sqrt(1.0 + 4.0 * t * t));
        float mom = (float)((t - 1.0) / tn);
        t = tn;
        if (it < FAST_ITERS) {
            k_g1f<<<dim3(16, SPLITK), 256, 0, stream>>>(Zh, Dth, Uph);
            k_redF<<<512, 256, 0, stream>>>(Uph, Eh, emb);
            if (it == FAST_ITERS - 1)
                k_g2f<1><<<dim3(314, 1), 256, 0, stream>>>(Eh, Dh, Wh, W,
                                                           Zh, Zl, scal, mom);
            else
                k_g2f<0><<<dim3(314, 1), 256, 0, stream>>>(Eh, Dh, Wh, W,
                                                           Zh, Zl, scal, mom);
        } else {
            k_g1p<<<dim3(16, SPLITK), 256, 0, stream>>>(Zh, Zl, Dth, Dtl, Up);
            k_redP<<<512, 256, 0, stream>>>(Up, Eh, El, emb, 0);
            k_g2p<<<dim3(314, 1), 256, 0, stream>>>(Eh, El, Dh, Dl, W, Zh, Zl,
                                                    scal, mom,
                                                    (it == N_ITERS - 1) ? 1 : 0);
        }
    }

    // ---- recon = W@D (Zh/Zl hold split W), score ----
    k_g1p<<<dim3(16, SPLITK), 256, 0, stream>>>(Zh, Zl, Dth, Dtl, Up);
    k_redP<<<512, 256, 0, stream>>>(Up, Eh, El, emb, 1);
    k_score<<<32, 256, 0, stream>>>(Eh, El, emb, out + (size_t)B_DIM * K_DIM);
}